// Round 5
// baseline (832.692 us; speedup 1.0000x reference)
//
#include <hip/hip_runtime.h>
#include <hip/hip_bf16.h>
#include <math.h>

#define BB   64
#define SS   100
#define BS   6400      // BB*SS
#define HD   129
#define ND   128
#define NPOI 10000
#define NCAT 500
#define NGEO 1000

typedef short short8 __attribute__((ext_vector_type(8)));
typedef float f32x4 __attribute__((ext_vector_type(4)));

#define MFMAB(a, b, c) __builtin_amdgcn_mfma_f32_16x16x32_bf16((a), (b), (c), 0, 0, 0)

__device__ inline unsigned short f2bf(float x) {
    union { float f; unsigned int u; } v; v.f = x;
    unsigned int r = v.u + 0x7fffu + ((v.u >> 16) & 1u);   // RNE
    return (unsigned short)(r >> 16);
}
__device__ inline float bf2f(unsigned short b) {
    union { float f; unsigned int u; } v; v.u = ((unsigned int)b) << 16;
    return v.f;
}

// ---------------------------------------------------------------------------
// K0: checkin = projx(0.3*poi + 0.1*cat + 0.1*geo + 0.5*user)  (spatial parts)
// ---------------------------------------------------------------------------
__global__ __launch_bounds__(128)
void checkin_kernel(const int* __restrict__ poi_seqs, const int* __restrict__ cat_seqs,
                    const int* __restrict__ geo_seqs, const int* __restrict__ user_list,
                    const float* __restrict__ poi_emb, const float* __restrict__ cat_emb,
                    const float* __restrict__ geo_emb, const float* __restrict__ user_emb,
                    float* __restrict__ checkin)
{
    __shared__ float red[128];
    int bs = blockIdx.x;
    int d  = threadIdx.x;
    int b  = bs / SS;
    int p = poi_seqs[bs], c = cat_seqs[bs], g = geo_seqs[bs], u = user_list[b];
    float sp = 0.3f * poi_emb[p * HD + 1 + d]
             + 0.1f * cat_emb[c * HD + 1 + d]
             + 0.1f * geo_emb[g * HD + 1 + d]
             + 0.5f * user_emb[u * HD + 1 + d];
    checkin[bs * HD + 1 + d] = sp;
    red[d] = sp * sp;
    __syncthreads();
    for (int off = 64; off > 0; off >>= 1) {
        if (d < off) red[d] += red[d + off];
        __syncthreads();
    }
    if (d == 0) checkin[bs * HD] = sqrtf(1.0f + red[0]);
}

// ---------------------------------------------------------------------------
// Pack: WT (d-major transposes of Wq/Wk/Wv)
// ---------------------------------------------------------------------------
__global__ void pack_wt_kernel(const float* __restrict__ Wq, const float* __restrict__ Wk,
                               const float* __restrict__ Wv, float* __restrict__ wt)
{
    int mat = blockIdx.y;
    const float* W = (mat == 0) ? Wq : ((mat == 1) ? Wk : Wv);
    int idx = blockIdx.x * 256 + threadIdx.x;
    if (idx >= HD * HD) return;
    int dd = idx / HD, j = idx % HD;
    wt[mat * HD * HD + idx] = W[j * HD + dd];
}

// ---------------------------------------------------------------------------
// Pack: split-bf16 B matrices (hi + residual*256).
// rows: [0,10000) poi, [10000,10500) cat, [10500,11500) geo
// ---------------------------------------------------------------------------
__global__ __launch_bounds__(128)
void pack_de_kernel(const float* __restrict__ Wd_poi, const float* __restrict__ Wd_cat,
                    const float* __restrict__ Wd_geo, const float* __restrict__ poi_emb,
                    const float* __restrict__ cat_emb, const float* __restrict__ geo_emb,
                    unsigned short* __restrict__ wph, unsigned short* __restrict__ wpl,
                    unsigned short* __restrict__ eph, unsigned short* __restrict__ epl)
{
    int r = blockIdx.x;
    int t = threadIdx.x;
    const float* Wsrc;
    const float* Esrc;
    int rl;
    if (r < NPOI)             { Wsrc = Wd_poi; Esrc = poi_emb; rl = r; }
    else if (r < NPOI + NCAT) { Wsrc = Wd_cat; Esrc = cat_emb; rl = r - NPOI; }
    else                      { Wsrc = Wd_geo; Esrc = geo_emb; rl = r - NPOI - NCAT; }
    size_t o = (size_t)r * ND + t;
    if (blockIdx.y == 0) {
        float v = Wsrc[rl * HD + 1 + t];
        unsigned short hh = f2bf(v);
        wph[o] = hh;
        wpl[o] = f2bf((v - bf2f(hh)) * 256.0f);
    } else {
        float v = Esrc[rl * HD + 1 + t];
        unsigned short hh = f2bf(v);
        eph[o] = hh;
        epl[o] = f2bf((v - bf2f(hh)) * 256.0f);
    }
}

// ---------------------------------------------------------------------------
// Pack: cos/sin tables for the 3 rotation heads
// ---------------------------------------------------------------------------
__global__ void pack_cs_kernel(const float* __restrict__ th_poi, const float* __restrict__ th_cat,
                               const float* __restrict__ th_geo, float* __restrict__ cs)
{
    int t = threadIdx.x;           // 0..191
    int h = t >> 6, i = t & 63;
    const float* th = (h == 0) ? th_poi : ((h == 1) ? th_cat : th_geo);
    cs[t * 2]     = cosf(th[i]);
    cs[t * 2 + 1] = sinf(th[i]);
}

// ---------------------------------------------------------------------------
// K2: q/k/v = checkin @ W^T + b
// ---------------------------------------------------------------------------
__global__ __launch_bounds__(256)
void qkv_kernel(const float* __restrict__ x, const float* __restrict__ wt,
                const float* __restrict__ bq, const float* __restrict__ bk,
                const float* __restrict__ bv,
                float* __restrict__ q, float* __restrict__ k, float* __restrict__ v)
{
    int mat = blockIdx.y;
    const float* W    = wt + mat * HD * HD;
    const float* bias = (mat == 0) ? bq : ((mat == 1) ? bk : bv);
    float* out        = (mat == 0) ? q  : ((mat == 1) ? k  : v);
    int o = blockIdx.x * 256 + threadIdx.x;
    if (o >= 1600 * HD) return;
    int j  = o % HD;
    int rr = o / HD;   // 0..1599
    const float* x0 = x + (size_t)rr * HD;
    const float* x1 = x0 + 1600 * HD;
    const float* x2 = x1 + 1600 * HD;
    const float* x3 = x2 + 1600 * HD;
    float a0 = 0.f, a1 = 0.f, a2 = 0.f, a3 = 0.f;
    #pragma unroll 8
    for (int d = 0; d < HD; ++d) {
        float w = W[d * HD + j];
        a0 += x0[d] * w;
        a1 += x1[d] * w;
        a2 += x2[d] * w;
        a3 += x3[d] * w;
    }
    float bb = bias[j];
    out[(size_t)rr * HD + j]          = a0 + bb;
    out[(size_t)(rr + 1600) * HD + j] = a1 + bb;
    out[(size_t)(rr + 3200) * HD + j] = a2 + bb;
    out[(size_t)(rr + 4800) * HD + j] = a3 + bb;
}

// ---------------------------------------------------------------------------
// K3: attention for one (b,s): scores -> softmax -> m -> traj -> rotate x3,
// emitting t as split-bf16 (hi + residual*256)
// ---------------------------------------------------------------------------
__global__ __launch_bounds__(192)
void attn_kernel(const float* __restrict__ q, const float* __restrict__ k,
                 const float* __restrict__ v, const int* __restrict__ poi_seqs,
                 const float* __restrict__ cs,
                 unsigned short* __restrict__ th_out, unsigned short* __restrict__ tl_out)
{
    __shared__ float qrow[HD];
    __shared__ float sc[128];
    __shared__ float red[128];
    __shared__ float xm[HD];
    int tid = threadIdx.x;
    int bs  = blockIdx.x;
    int b   = bs / SS;

    for (int d = tid; d < HD; d += 192) qrow[d] = q[(size_t)bs * HD + d];
    __syncthreads();

    float score = -INFINITY;
    if (tid < SS) {
        const float* kr = k + (size_t)(b * SS + tid) * HD;
        float ss = -qrow[0] * kr[0];
        #pragma unroll 8
        for (int d = 1; d < HD; ++d) ss += qrow[d] * kr[d];
        score = (2.0f + 2.0f * ss) * (1.0f / sqrtf(129.0f));
        if (poi_seqs[b * SS + tid] == NPOI) score = -1e9f;
    }
    if (tid < 128) sc[tid] = score;
    __syncthreads();

    if (tid < 128) red[tid] = sc[tid];
    __syncthreads();
    for (int off = 64; off > 0; off >>= 1) {
        if (tid < off) red[tid] = fmaxf(red[tid], red[tid + off]);
        __syncthreads();
    }
    float smax = red[0];
    __syncthreads();
    float e = 0.f;
    if (tid < 128) { e = __expf(sc[tid] - smax); red[tid] = e; }
    __syncthreads();
    for (int off = 64; off > 0; off >>= 1) {
        if (tid < off) red[tid] += red[tid + off];
        __syncthreads();
    }
    float inv = 1.0f / red[0];
    __syncthreads();
    if (tid < 128) sc[tid] = e * inv;
    __syncthreads();

    if (tid < HD) {
        float acc = 0.f;
        const float* vb = v + (size_t)b * SS * HD + tid;
        #pragma unroll 4
        for (int t = 0; t < SS; ++t) acc += sc[t] * vb[t * HD];
        xm[tid] = acc;
    }
    __syncthreads();

    if (tid < 128) { float mv = xm[1 + tid]; red[tid] = mv * mv; }
    __syncthreads();
    for (int off = 64; off > 0; off >>= 1) {
        if (tid < off) red[tid] += red[tid + off];
        __syncthreads();
    }
    float m0 = xm[0];
    float denom = sqrtf(fmaxf(m0 * m0 - red[0], 1e-6f));
    float invd = 1.0f / denom;

    if (tid < 64) {
        int i = tid;
        float av  = xm[1 + 2 * i] * invd;
        float bv2 = xm[2 + 2 * i] * invd;
        #pragma unroll
        for (int h = 0; h < 3; ++h) {
            float cth = cs[(h * 64 + i) * 2];
            float sth = cs[(h * 64 + i) * 2 + 1];
            float x0 = av * cth - bv2 * sth;
            float x1 = av * sth + bv2 * cth;
            size_t base = (size_t)h * BS * ND + (size_t)bs * ND + 2 * i;
            unsigned short h0 = f2bf(x0);
            unsigned short h1 = f2bf(x1);
            th_out[base]     = h0;
            th_out[base + 1] = h1;
            tl_out[base]     = f2bf((x0 - bf2f(h0)) * 256.0f);
            tl_out[base + 1] = f2bf((x1 - bf2f(h1)) * 256.0f);
        }
    }
}

// ---------------------------------------------------------------------------
// K4: MFMA head GEMM (split-bf16, 3-term):
//   dot(A,B) ~= Ah.Bh + (Ah.Bl + Al.Bh)/256
//   out[m,n] = linW + bd[n] + exp(min(2 + 2*linE, 86))
// Block 128(M)x64(N), 4 waves, wave tile 32x64, no LDS (B is L2-resident).
// ---------------------------------------------------------------------------
__global__ __launch_bounds__(256, 2)
void gemm_head_mfma(const unsigned short* __restrict__ Ah, const unsigned short* __restrict__ Al,
                    const unsigned short* __restrict__ Bwh, const unsigned short* __restrict__ Bwl,
                    const unsigned short* __restrict__ Beh, const unsigned short* __restrict__ Bel,
                    const float* __restrict__ bd, float* __restrict__ out, int N)
{
    int lane = threadIdx.x & 63;
    int w    = threadIdx.x >> 6;          // 0..3
    int m0   = blockIdx.y * 128 + w * 32; // wave's 32 rows
    int n0   = blockIdx.x * 64;
    int lr   = lane & 15;                 // row-in-frag / col-in-frag
    int lg   = lane >> 4;                 // k-group

    f32x4 accWP[2][4] = {};
    f32x4 accWQ[2][4] = {};
    f32x4 accEP[2][4] = {};
    f32x4 accEQ[2][4] = {};

    #pragma unroll
    for (int kc = 0; kc < 4; ++kc) {
        int koff = kc * 32 + lg * 8;
        short8 a0h = *(const short8*)&Ah[(size_t)(m0 + lr) * ND + koff];
        short8 a0l = *(const short8*)&Al[(size_t)(m0 + lr) * ND + koff];
        short8 a1h = *(const short8*)&Ah[(size_t)(m0 + 16 + lr) * ND + koff];
        short8 a1l = *(const short8*)&Al[(size_t)(m0 + 16 + lr) * ND + koff];
        #pragma unroll
        for (int c = 0; c < 4; ++c) {
            int nr = n0 + c * 16 + lr;
            if (nr >= N) nr = N - 1;
            size_t bo = (size_t)nr * ND + koff;
            short8 bwh = *(const short8*)&Bwh[bo];
            short8 bwl = *(const short8*)&Bwl[bo];
            short8 beh = *(const short8*)&Beh[bo];
            short8 bel = *(const short8*)&Bel[bo];
            accWP[0][c] = MFMAB(a0h, bwh, accWP[0][c]);
            accWQ[0][c] = MFMAB(a0h, bwl, accWQ[0][c]);
            accWQ[0][c] = MFMAB(a0l, bwh, accWQ[0][c]);
            accEP[0][c] = MFMAB(a0h, beh, accEP[0][c]);
            accEQ[0][c] = MFMAB(a0h, bel, accEQ[0][c]);
            accEQ[0][c] = MFMAB(a0l, beh, accEQ[0][c]);
            accWP[1][c] = MFMAB(a1h, bwh, accWP[1][c]);
            accWQ[1][c] = MFMAB(a1h, bwl, accWQ[1][c]);
            accWQ[1][c] = MFMAB(a1l, bwh, accWQ[1][c]);
            accEP[1][c] = MFMAB(a1h, beh, accEP[1][c]);
            accEQ[1][c] = MFMAB(a1h, bel, accEQ[1][c]);
            accEQ[1][c] = MFMAB(a1l, beh, accEQ[1][c]);
        }
    }

    const float s2 = 1.0f / 256.0f;
    #pragma unroll
    for (int r = 0; r < 2; ++r) {
        #pragma unroll
        for (int c = 0; c < 4; ++c) {
            int n = n0 + c * 16 + lr;
            if (n >= N) continue;
            float bdv = bd[n];
            #pragma unroll
            for (int d = 0; d < 4; ++d) {
                int row = m0 + r * 16 + lg * 4 + d;
                float lin = accWP[r][c][d] + accWQ[r][c][d] * s2;
                float uv  = accEP[r][c][d] + accEQ[r][c][d] * s2;
                float arg = fminf(2.0f + 2.0f * uv, 86.0f);
                out[(size_t)row * N + n] = lin + bdv + __expf(arg);
            }
        }
    }
}

// ---------------------------------------------------------------------------
extern "C" void kernel_launch(void* const* d_in, const int* in_sizes, int n_in,
                              void* d_out, int out_size, void* d_ws, size_t ws_size,
                              hipStream_t stream)
{
    const int* poi_seqs  = (const int*)d_in[0];
    const int* cat_seqs  = (const int*)d_in[1];
    const int* geo_seqs  = (const int*)d_in[2];
    const int* user_list = (const int*)d_in[3];
    const float* poi_emb = (const float*)d_in[4];
    const float* cat_emb = (const float*)d_in[5];
    const float* geo_emb = (const float*)d_in[6];
    const float* user_emb= (const float*)d_in[7];
    const float* th_poi  = (const float*)d_in[8];
    const float* th_cat  = (const float*)d_in[9];
    const float* th_geo  = (const float*)d_in[10];
    const float* Wq      = (const float*)d_in[11];
    const float* bq      = (const float*)d_in[12];
    const float* Wk      = (const float*)d_in[13];
    const float* bk      = (const float*)d_in[14];
    const float* Wv      = (const float*)d_in[15];
    const float* bv      = (const float*)d_in[16];
    const float* Wd_poi  = (const float*)d_in[17];
    const float* bd_poi  = (const float*)d_in[18];
    const float* Wd_cat  = (const float*)d_in[19];
    const float* bd_cat  = (const float*)d_in[20];
    const float* Wd_geo  = (const float*)d_in[21];
    const float* bd_geo  = (const float*)d_in[22];

    float* ws      = (float*)d_ws;
    float* checkin = ws + 0;        // 825,600 f32
    float* qbuf    = ws + 1000000;  // 825,600 f32
    float* kbuf    = ws + 2000000;
    float* vbuf    = ws + 3000000;
    float* wt      = ws + 4000000;  // 49,923 f32
    float* cs      = ws + 4100000;  // 384 f32
    unsigned short* tallh = (unsigned short*)(ws + 4200000);  // 2,457,600 u16
    unsigned short* talll = (unsigned short*)(ws + 5500000);  // 2,457,600 u16
    unsigned short* wph   = (unsigned short*)(ws + 6800000);  // 1,472,000 u16
    unsigned short* wpl   = (unsigned short*)(ws + 7600000);
    unsigned short* eph   = (unsigned short*)(ws + 8400000);
    unsigned short* epl   = (unsigned short*)(ws + 9200000);
    float* out     = (float*)d_out;

    checkin_kernel<<<BS, 128, 0, stream>>>(poi_seqs, cat_seqs, geo_seqs, user_list,
                                           poi_emb, cat_emb, geo_emb, user_emb, checkin);
    pack_wt_kernel<<<dim3(66, 3), 256, 0, stream>>>(Wq, Wk, Wv, wt);
    pack_de_kernel<<<dim3(11500, 2), 128, 0, stream>>>(Wd_poi, Wd_cat, Wd_geo,
                                                       poi_emb, cat_emb, geo_emb,
                                                       wph, wpl, eph, epl);
    pack_cs_kernel<<<1, 192, 0, stream>>>(th_poi, th_cat, th_geo, cs);
    qkv_kernel<<<dim3(807, 3), 256, 0, stream>>>(checkin, wt, bq, bk, bv, qbuf, kbuf, vbuf);
    attn_kernel<<<BS, 192, 0, stream>>>(qbuf, kbuf, vbuf, poi_seqs, cs, tallh, talll);

    // poi head: A rows [0,6400), B rows [0,10000)
    gemm_head_mfma<<<dim3(157, 50), 256, 0, stream>>>(
        tallh, talll, wph, wpl, eph, epl, bd_poi, out, NPOI);
    // cat head
    gemm_head_mfma<<<dim3(8, 50), 256, 0, stream>>>(
        tallh + (size_t)BS * ND, talll + (size_t)BS * ND,
        wph + (size_t)NPOI * ND, wpl + (size_t)NPOI * ND,
        eph + (size_t)NPOI * ND, epl + (size_t)NPOI * ND,
        bd_cat, out + 64000000, NCAT);
    // geo head
    gemm_head_mfma<<<dim3(16, 50), 256, 0, stream>>>(
        tallh + 2 * (size_t)BS * ND, talll + 2 * (size_t)BS * ND,
        wph + (size_t)(NPOI + NCAT) * ND, wpl + (size_t)(NPOI + NCAT) * ND,
        eph + (size_t)(NPOI + NCAT) * ND, epl + (size_t)(NPOI + NCAT) * ND,
        bd_geo, out + 67200000, NGEO);
}